// Round 1
// baseline (1091.935 us; speedup 1.0000x reference)
//
#include <hip/hip_runtime.h>
#include <hip/hip_bf16.h>

#define N_NODES 100000
#define N_EDGES 1600000

// ---------------- CSR build ----------------

__global__ void hist_kernel(const int* __restrict__ dst, int* __restrict__ cnt, int E) {
    int e = blockIdx.x * blockDim.x + threadIdx.x;
    if (e < E) atomicAdd(&cnt[dst[e]], 1);
}

// CHUNK=2048 per block, 256 threads x 8 elems
__global__ void scan1_kernel(const int* __restrict__ cnt, int* __restrict__ row_ptr,
                             float* __restrict__ inv_deg, int* __restrict__ blockSums, int n) {
    constexpr int T = 256, PER = 8, CHUNK = T * PER;
    __shared__ int sdata[T];
    int base = blockIdx.x * CHUNK + threadIdx.x * PER;
    int v[PER];
    int s = 0;
#pragma unroll
    for (int i = 0; i < PER; i++) {
        int idx = base + i;
        int c = (idx < n) ? cnt[idx] : 0;
        v[i] = c; s += c;
    }
    sdata[threadIdx.x] = s;
    __syncthreads();
    for (int off = 1; off < T; off <<= 1) {
        int x = sdata[threadIdx.x];
        int y = (threadIdx.x >= off) ? sdata[threadIdx.x - off] : 0;
        __syncthreads();
        sdata[threadIdx.x] = x + y;
        __syncthreads();
    }
    int excl = sdata[threadIdx.x] - s;
    if (threadIdx.x == T - 1) blockSums[blockIdx.x] = sdata[T - 1];
    int run = excl;
#pragma unroll
    for (int i = 0; i < PER; i++) {
        int idx = base + i;
        if (idx < n) {
            row_ptr[idx] = run;
            int d = v[i] > 1 ? v[i] : 1;
            inv_deg[idx] = 1.0f / (float)d;
        }
        run += v[i];
    }
}

__global__ void scan2_kernel(const int* __restrict__ blockSums, int* __restrict__ blockOfs,
                             int nblocks, int* __restrict__ row_ptr, int n) {
    if (threadIdx.x == 0 && blockIdx.x == 0) {
        int run = 0;
        for (int b = 0; b < nblocks; b++) {
            int t = blockSums[b];
            blockOfs[b] = run;
            run += t;
        }
        row_ptr[n] = run;
    }
}

__global__ void scan3_kernel(int* __restrict__ row_ptr, const int* __restrict__ blockOfs,
                             int* __restrict__ cursor, int n) {
    int i = blockIdx.x * blockDim.x + threadIdx.x;
    if (i < n) {
        int v = row_ptr[i] + blockOfs[i / 2048];
        row_ptr[i] = v;
        cursor[i] = v;
    }
}

__global__ void fill_kernel(const int* __restrict__ src, const int* __restrict__ dst,
                            int* __restrict__ cursor, int* __restrict__ col, int E) {
    int e = blockIdx.x * blockDim.x + threadIdx.x;
    if (e < E) {
        int d = dst[e];
        int pos = atomicAdd(&cursor[d], 1);
        col[pos] = src[e];
    }
}

// ---------------- Aggregation: one wave per node, float2/lane over 128 feats ----------------

__global__ __launch_bounds__(256) void agg_kernel(const float* __restrict__ h,
                                                  const int* __restrict__ row_ptr,
                                                  const int* __restrict__ col,
                                                  const float* __restrict__ inv_deg,
                                                  float* __restrict__ agg, int n) {
    int wave = (int)((blockIdx.x * blockDim.x + threadIdx.x) >> 6);
    int lane = threadIdx.x & 63;
    if (wave >= n) return;
    int beg = row_ptr[wave], end = row_ptr[wave + 1];
    float ax = 0.f, ay = 0.f;
    for (int e = beg; e < end; e++) {
        int s = col[e];
        float2 v = ((const float2*)(h + (size_t)s * 128))[lane];
        ax += v.x; ay += v.y;
    }
    float inv = inv_deg[wave];
    float2 o; o.x = ax * inv; o.y = ay * inv;
    ((float2*)(agg + (size_t)wave * 128))[lane] = o;
}

// ---------------- GEMM: out[n][j] = sum_k h[n][k]*Ws[k][j] + agg[n][k]*Wn[k][j] + b[j] ----------------
// M-tile 64 nodes x full FOUT, K=256 in chunks of 32. fp32 vector ALU (no fp32 MFMA on CDNA4).

template <int FOUT, bool RELU>
__global__ __launch_bounds__(256) void gemm_kernel(const float* __restrict__ Hself,
                                                   const float* __restrict__ Hagg,
                                                   const float* __restrict__ Ws,
                                                   const float* __restrict__ Wn,
                                                   const float* __restrict__ bias,
                                                   float* __restrict__ out, int nNodes) {
    constexpr int MT = 64;
    constexpr int KC = 32;
    constexpr int JPT = FOUT / 32;  // 4 (FOUT=128) or 2 (FOUT=64)
    // pad A stride to 68 floats: 272 B = 17*16 keeps rows 16B-aligned for ds_read_b128
    __shared__ float As[KC][MT + 4];
    __shared__ float Bs[KC][FOUT];

    int tid = threadIdx.x;
    int node0 = blockIdx.x * MT;
    int it = tid >> 5;   // 0..7: node group (8 nodes each)
    int jt = tid & 31;   // col group (JPT cols each)

    float acc[8][JPT];
#pragma unroll
    for (int a = 0; a < 8; a++)
#pragma unroll
        for (int b = 0; b < JPT; b++) acc[a][b] = 0.f;

    for (int k0 = 0; k0 < 256; k0 += KC) {
        const float* Asrc = (k0 < 128) ? Hself : Hagg;
        const float* Bsrc = (k0 < 128) ? Ws : Wn;
        int kbase = (k0 < 128) ? k0 : (k0 - 128);
        // stage A: 64 nodes x 32 k
        {
            int kk = tid & 31;
            int nl0 = tid >> 5;
#pragma unroll
            for (int r = 0; r < 8; r++) {
                int nl = nl0 + r * 8;
                int n = node0 + nl;
                float v = (n < nNodes) ? Asrc[(size_t)n * 128 + kbase + kk] : 0.f;
                As[kk][nl] = v;
            }
        }
        // stage B: 32 k x FOUT
        {
            constexpr int TOT = KC * FOUT;
            constexpr int PER = TOT / 256;
#pragma unroll
            for (int r = 0; r < PER; r++) {
                int idx = tid + r * 256;
                int kk = idx / FOUT;
                int j = idx % FOUT;
                Bs[kk][j] = Bsrc[(size_t)(kbase + kk) * FOUT + j];
            }
        }
        __syncthreads();
#pragma unroll
        for (int kk = 0; kk < KC; kk++) {
            float a[8], b[JPT];
#pragma unroll
            for (int x = 0; x < 8; x++) a[x] = As[kk][it * 8 + x];
#pragma unroll
            for (int y = 0; y < JPT; y++) b[y] = Bs[kk][jt * JPT + y];
#pragma unroll
            for (int x = 0; x < 8; x++)
#pragma unroll
                for (int y = 0; y < JPT; y++) acc[x][y] += a[x] * b[y];
        }
        __syncthreads();
    }
#pragma unroll
    for (int x = 0; x < 8; x++) {
        int n = node0 + it * 8 + x;
        if (n < nNodes) {
#pragma unroll
            for (int y = 0; y < JPT; y++) {
                int j = jt * JPT + y;
                float v = acc[x][y] + bias[j];
                if (RELU) v = fmaxf(v, 0.f);
                out[(size_t)n * FOUT + j] = v;
            }
        }
    }
}

extern "C" void kernel_launch(void* const* d_in, const int* in_sizes, int n_in,
                              void* d_out, int out_size, void* d_ws, size_t ws_size,
                              hipStream_t stream) {
    const float* x   = (const float*)d_in[0];
    const int* src   = (const int*)d_in[1];
    const int* dst   = (const int*)d_in[2];
    const float* Ws0 = (const float*)d_in[3];
    const float* Wn0 = (const float*)d_in[4];
    const float* b0  = (const float*)d_in[5];
    const float* Ws1 = (const float*)d_in[6];
    const float* Wn1 = (const float*)d_in[7];
    const float* b1  = (const float*)d_in[8];
    const float* Ws2 = (const float*)d_in[9];
    const float* Wn2 = (const float*)d_in[10];
    const float* b2  = (const float*)d_in[11];
    float* out = (float*)d_out;

    const int N = N_NODES, E = N_EDGES;

    char* p = (char*)d_ws;
    auto take = [&](size_t bytes) {
        void* r = (void*)p;
        p += (bytes + 255) & ~(size_t)255;
        return r;
    };
    int* cnt       = (int*)take((size_t)N * 4);        // also reused as CSR fill cursor
    int* row_ptr   = (int*)take((size_t)(N + 1) * 4);
    int* blockSums = (int*)take(64 * 4);
    int* blockOfs  = (int*)take(64 * 4);
    int* col       = (int*)take((size_t)E * 4);
    float* inv_deg = (float*)take((size_t)N * 4);
    float* hA      = (float*)take((size_t)N * 128 * 4);
    float* agg     = (float*)take((size_t)N * 128 * 4);
    // layer-1 output goes into the x input buffer (restored by harness each launch)
    float* xbuf = (float*)d_in[0];

    // --- CSR build ---
    hipMemsetAsync(cnt, 0, (size_t)N * 4, stream);
    hist_kernel<<<(E + 255) / 256, 256, 0, stream>>>(dst, cnt, E);
    int nchunks = (N + 2047) / 2048;  // 49
    scan1_kernel<<<nchunks, 256, 0, stream>>>(cnt, row_ptr, inv_deg, blockSums, N);
    scan2_kernel<<<1, 64, 0, stream>>>(blockSums, blockOfs, nchunks, row_ptr, N);
    scan3_kernel<<<(N + 255) / 256, 256, 0, stream>>>(row_ptr, blockOfs, cnt, N);
    fill_kernel<<<(E + 255) / 256, 256, 0, stream>>>(src, dst, cnt, col, E);

    int aggGrid = (N * 64 + 255) / 256;  // one wave per node
    int gemmGrid = (N + 63) / 64;

    // --- layer 0 ---
    agg_kernel<<<aggGrid, 256, 0, stream>>>(x, row_ptr, col, inv_deg, agg, N);
    gemm_kernel<128, true><<<gemmGrid, 256, 0, stream>>>(x, agg, Ws0, Wn0, b0, hA, N);
    // --- layer 1 ---
    agg_kernel<<<aggGrid, 256, 0, stream>>>(hA, row_ptr, col, inv_deg, agg, N);
    gemm_kernel<128, true><<<gemmGrid, 256, 0, stream>>>(hA, agg, Ws1, Wn1, b1, xbuf, N);
    // --- layer 2 ---
    agg_kernel<<<aggGrid, 256, 0, stream>>>(xbuf, row_ptr, col, inv_deg, agg, N);
    gemm_kernel<64, false><<<gemmGrid, 256, 0, stream>>>(xbuf, agg, Ws2, Wn2, b2, out, N);
}

// Round 2
// 668.615 us; speedup vs baseline: 1.6331x; 1.6331x over previous
//
#include <hip/hip_runtime.h>
#include <hip/hip_bf16.h>

#define N_NODES 100000
#define N_EDGES 1600000

typedef __attribute__((ext_vector_type(8))) short short8;
typedef __attribute__((ext_vector_type(4))) float f32x4;
typedef unsigned short ushort;
typedef unsigned int uint;

__device__ __forceinline__ ushort f2bf(float f) {
    uint u = __float_as_uint(f);
    uint r = (u + 0x7fffu + ((u >> 16) & 1u)) >> 16;
    return (ushort)r;
}
__device__ __forceinline__ float bflo(uint v) { return __uint_as_float(v << 16); }
__device__ __forceinline__ float bfhi(uint v) { return __uint_as_float(v & 0xffff0000u); }

// ---------------- CSR build ----------------

__global__ void hist_kernel(const int* __restrict__ dst, int* __restrict__ cnt, int E) {
    int e = blockIdx.x * blockDim.x + threadIdx.x;
    if (e < E) atomicAdd(&cnt[dst[e]], 1);
}

__global__ void scan1_kernel(const int* __restrict__ cnt, int* __restrict__ row_ptr,
                             float* __restrict__ inv_deg, int* __restrict__ blockSums, int n) {
    constexpr int T = 256, PER = 8, CHUNK = T * PER;
    __shared__ int sdata[T];
    int base = blockIdx.x * CHUNK + threadIdx.x * PER;
    int v[PER];
    int s = 0;
#pragma unroll
    for (int i = 0; i < PER; i++) {
        int idx = base + i;
        int c = (idx < n) ? cnt[idx] : 0;
        v[i] = c; s += c;
    }
    sdata[threadIdx.x] = s;
    __syncthreads();
    for (int off = 1; off < T; off <<= 1) {
        int x = sdata[threadIdx.x];
        int y = (threadIdx.x >= off) ? sdata[threadIdx.x - off] : 0;
        __syncthreads();
        sdata[threadIdx.x] = x + y;
        __syncthreads();
    }
    int excl = sdata[threadIdx.x] - s;
    if (threadIdx.x == T - 1) blockSums[blockIdx.x] = sdata[T - 1];
    int run = excl;
#pragma unroll
    for (int i = 0; i < PER; i++) {
        int idx = base + i;
        if (idx < n) {
            row_ptr[idx] = run;
            int d = v[i] > 1 ? v[i] : 1;
            inv_deg[idx] = 1.0f / (float)d;
        }
        run += v[i];
    }
}

__global__ void scan2_kernel(const int* __restrict__ blockSums, int* __restrict__ blockOfs,
                             int nblocks, int* __restrict__ row_ptr, int n) {
    if (threadIdx.x == 0 && blockIdx.x == 0) {
        int run = 0;
        for (int b = 0; b < nblocks; b++) {
            int t = blockSums[b];
            blockOfs[b] = run;
            run += t;
        }
        row_ptr[n] = run;
    }
}

__global__ void scan3_kernel(int* __restrict__ row_ptr, const int* __restrict__ blockOfs,
                             int* __restrict__ cursor, int n) {
    int i = blockIdx.x * blockDim.x + threadIdx.x;
    if (i < n) {
        int v = row_ptr[i] + blockOfs[i / 2048];
        row_ptr[i] = v;
        cursor[i] = v;
    }
}

__global__ void fill_kernel(const int* __restrict__ src, const int* __restrict__ dst,
                            int* __restrict__ cursor, int* __restrict__ col, int E) {
    int e = blockIdx.x * blockDim.x + threadIdx.x;
    if (e < E) {
        int d = dst[e];
        int pos = atomicAdd(&cursor[d], 1);
        col[pos] = src[e];
    }
}

// ---------------- cast fp32 -> bf16 (x input) ----------------

__global__ __launch_bounds__(256) void cast_x_kernel(const float* __restrict__ x,
                                                     ushort* __restrict__ xb, long n8) {
    long g = (long)blockIdx.x * blockDim.x + threadIdx.x;
    if (g >= n8) return;
    const float4* x4 = (const float4*)x;
    float4 a = x4[g * 2], b = x4[g * 2 + 1];
    uint4 o;
    o.x = (uint)f2bf(a.x) | ((uint)f2bf(a.y) << 16);
    o.y = (uint)f2bf(a.z) | ((uint)f2bf(a.w) << 16);
    o.z = (uint)f2bf(b.x) | ((uint)f2bf(b.y) << 16);
    o.w = (uint)f2bf(b.z) | ((uint)f2bf(b.w) << 16);
    ((uint4*)xb)[g] = o;
}

// ---------------- weight transpose+cast: BT[n][k], k<128 -> Ws, else Wn ----------------

__global__ void mk_bt_kernel(const float* __restrict__ Ws, const float* __restrict__ Wn,
                             ushort* __restrict__ BT, int FOUT) {
    int idx = blockIdx.x * blockDim.x + threadIdx.x;  // n*256 + k
    if (idx >= FOUT * 256) return;
    int n = idx >> 8, k = idx & 255;
    float v = (k < 128) ? Ws[k * FOUT + n] : Wn[(k - 128) * FOUT + n];
    BT[idx] = f2bf(v);
}

// ---------------- Aggregation: one wave per node, bf16 gather, fp32 accumulate ----------------

__global__ __launch_bounds__(256) void agg_kernel(const ushort* __restrict__ hb,
                                                  const int* __restrict__ row_ptr,
                                                  const int* __restrict__ col,
                                                  const float* __restrict__ inv_deg,
                                                  ushort* __restrict__ aggb, int n) {
    int node = (int)((blockIdx.x * blockDim.x + threadIdx.x) >> 6);
    int lane = threadIdx.x & 63;
    if (node >= n) return;
    const uint* h32 = (const uint*)hb;  // 64 uints per 128-feat row
    int beg = row_ptr[node], end = row_ptr[node + 1];
    float ax = 0.f, ay = 0.f, bx = 0.f, by = 0.f;
    int e = beg;
    for (; e + 2 <= end; e += 2) {
        int s0 = col[e], s1 = col[e + 1];
        uint v0 = h32[(size_t)s0 * 64 + lane];
        uint v1 = h32[(size_t)s1 * 64 + lane];
        ax += bflo(v0); ay += bfhi(v0);
        bx += bflo(v1); by += bfhi(v1);
    }
    if (e < end) {
        uint v0 = h32[(size_t)col[e] * 64 + lane];
        ax += bflo(v0); ay += bfhi(v0);
    }
    float inv = inv_deg[node];
    float ox = (ax + bx) * inv, oy = (ay + by) * inv;
    ((uint*)aggb)[(size_t)node * 64 + lane] = (uint)f2bf(ox) | ((uint)f2bf(oy) << 16);
}

// ---------------- MFMA GEMM: out[n][j] = [h|agg] @ BT^T + b ----------------
// Block: 256 threads = 4 waves; M-tile 64 (16 rows/wave), N = FOUT full, K = 256 in 8 chunks of 32.
// A-frags direct from global (16B/lane, 64B per row per K-step fully consumed).
// B staged per-chunk into LDS as BT[n][kk], stride 40 ushorts (2-way bank aliasing = free).

template <int FOUT, bool RELU, bool OUTBF16>
__global__ __launch_bounds__(256) void mfma_gemm(const ushort* __restrict__ hb,
                                                 const ushort* __restrict__ aggb,
                                                 const ushort* __restrict__ BTb,
                                                 const float* __restrict__ bias,
                                                 void* __restrict__ outp, int nNodes) {
    constexpr int NT = FOUT / 16;
    constexpr int BSTR = 40;
    __shared__ ushort BT[FOUT * BSTR];
    int tid = threadIdx.x;
    int wave = tid >> 6, lane = tid & 63;
    int m = lane & 15, quad = lane >> 4;
    int r0 = blockIdx.x * 64 + wave * 16;
    int arow = r0 + m;
    if (arow >= nNodes) arow = nNodes - 1;
    const ushort* hrow = hb + (size_t)arow * 128;
    const ushort* grow = aggb + (size_t)arow * 128;

    f32x4 acc[NT];
#pragma unroll
    for (int t = 0; t < NT; t++) acc[t] = (f32x4){0.f, 0.f, 0.f, 0.f};

#pragma unroll
    for (int kc = 0; kc < 8; kc++) {
        __syncthreads();
        // stage B chunk [FOUT][32] -> LDS
        constexpr int UNITS = FOUT * 4;  // 16B units
#pragma unroll
        for (int u0 = 0; u0 < UNITS / 256; u0++) {
            int u = tid + u0 * 256;
            int n = u >> 2, ko = (u & 3) * 8;
            short8 v = *(const short8*)(BTb + n * 256 + kc * 32 + ko);
            *(short8*)(&BT[n * BSTR + ko]) = v;
        }
        __syncthreads();
        int kg = kc * 32 + quad * 8;
        const ushort* ap = (kg < 128) ? (hrow + kg) : (grow + (kg - 128));
        short8 afrag = *(const short8*)ap;
#pragma unroll
        for (int t = 0; t < NT; t++) {
            short8 bfrag = *(const short8*)(&BT[(t * 16 + m) * BSTR + quad * 8]);
            acc[t] = __builtin_amdgcn_mfma_f32_16x16x32_bf16(afrag, bfrag, acc[t], 0, 0, 0);
        }
    }

#pragma unroll
    for (int reg = 0; reg < 4; reg++) {
        int orow = r0 + quad * 4 + reg;
        if (orow < nNodes) {
#pragma unroll
            for (int t = 0; t < NT; t++) {
                int j = t * 16 + m;
                float v = acc[t][reg] + bias[j];
                if (RELU) v = fmaxf(v, 0.f);
                if (OUTBF16)
                    ((ushort*)outp)[(size_t)orow * FOUT + j] = f2bf(v);
                else
                    ((float*)outp)[(size_t)orow * FOUT + j] = v;
            }
        }
    }
}

extern "C" void kernel_launch(void* const* d_in, const int* in_sizes, int n_in,
                              void* d_out, int out_size, void* d_ws, size_t ws_size,
                              hipStream_t stream) {
    const float* x   = (const float*)d_in[0];
    const int* src   = (const int*)d_in[1];
    const int* dst   = (const int*)d_in[2];
    const float* Ws0 = (const float*)d_in[3];
    const float* Wn0 = (const float*)d_in[4];
    const float* b0  = (const float*)d_in[5];
    const float* Ws1 = (const float*)d_in[6];
    const float* Wn1 = (const float*)d_in[7];
    const float* b1  = (const float*)d_in[8];
    const float* Ws2 = (const float*)d_in[9];
    const float* Wn2 = (const float*)d_in[10];
    const float* b2  = (const float*)d_in[11];
    float* out = (float*)d_out;

    const int N = N_NODES, E = N_EDGES;

    char* p = (char*)d_ws;
    auto take = [&](size_t bytes) {
        void* r = (void*)p;
        p += (bytes + 255) & ~(size_t)255;
        return r;
    };
    int* cnt       = (int*)take((size_t)N * 4);  // reused as CSR fill cursor
    int* row_ptr   = (int*)take((size_t)(N + 1) * 4);
    int* blockSums = (int*)take(64 * 4);
    int* blockOfs  = (int*)take(64 * 4);
    int* col       = (int*)take((size_t)E * 4);
    float* inv_deg = (float*)take((size_t)N * 4);
    ushort* xb     = (ushort*)take((size_t)N * 128 * 2);
    ushort* h1b    = (ushort*)take((size_t)N * 128 * 2);
    ushort* aggb   = (ushort*)take((size_t)N * 128 * 2);
    ushort* BT0    = (ushort*)take((size_t)128 * 256 * 2);
    ushort* BT1    = (ushort*)take((size_t)128 * 256 * 2);
    ushort* BT2    = (ushort*)take((size_t)64 * 256 * 2);

    // --- CSR build ---
    hipMemsetAsync(cnt, 0, (size_t)N * 4, stream);
    hist_kernel<<<(E + 255) / 256, 256, 0, stream>>>(dst, cnt, E);
    int nchunks = (N + 2047) / 2048;
    scan1_kernel<<<nchunks, 256, 0, stream>>>(cnt, row_ptr, inv_deg, blockSums, N);
    scan2_kernel<<<1, 64, 0, stream>>>(blockSums, blockOfs, nchunks, row_ptr, N);
    scan3_kernel<<<(N + 255) / 256, 256, 0, stream>>>(row_ptr, blockOfs, cnt, N);
    fill_kernel<<<(E + 255) / 256, 256, 0, stream>>>(src, dst, cnt, col, E);

    // --- casts / weight transposes ---
    long n8 = (long)N * 128 / 8;
    cast_x_kernel<<<(int)((n8 + 255) / 256), 256, 0, stream>>>(x, xb, n8);
    mk_bt_kernel<<<(128 * 256 + 255) / 256, 256, 0, stream>>>(Ws0, Wn0, BT0, 128);
    mk_bt_kernel<<<(128 * 256 + 255) / 256, 256, 0, stream>>>(Ws1, Wn1, BT1, 128);
    mk_bt_kernel<<<(64 * 256 + 255) / 256, 256, 0, stream>>>(Ws2, Wn2, BT2, 64);

    int aggGrid = (int)(((long)N * 64 + 255) / 256);
    int gemmGrid = (N + 63) / 64;

    // --- layer 0: xb -> h1b ---
    agg_kernel<<<aggGrid, 256, 0, stream>>>(xb, row_ptr, col, inv_deg, aggb, N);
    mfma_gemm<128, true, true><<<gemmGrid, 256, 0, stream>>>(xb, aggb, BT0, b0, h1b, N);
    // --- layer 1: h1b -> xb (reuse) ---
    agg_kernel<<<aggGrid, 256, 0, stream>>>(h1b, row_ptr, col, inv_deg, aggb, N);
    mfma_gemm<128, true, true><<<gemmGrid, 256, 0, stream>>>(h1b, aggb, BT1, b1, xb, N);
    // --- layer 2: xb -> out (fp32) ---
    agg_kernel<<<aggGrid, 256, 0, stream>>>(xb, row_ptr, col, inv_deg, aggb, N);
    mfma_gemm<64, false, false><<<gemmGrid, 256, 0, stream>>>(xb, aggb, BT2, b2, out, N);
}

// Round 3
// 601.086 us; speedup vs baseline: 1.8166x; 1.1123x over previous
//
#include <hip/hip_runtime.h>
#include <hip/hip_bf16.h>

#define N_NODES 100000
#define N_EDGES 1600000
#define CPAD 16  // one counter per 64B cacheline: kills cross-XCD line ping-pong serialization

typedef __attribute__((ext_vector_type(8))) short short8;
typedef __attribute__((ext_vector_type(4))) float f32x4;
typedef unsigned short ushort;
typedef unsigned int uint;

__device__ __forceinline__ ushort f2bf(float f) {
    uint u = __float_as_uint(f);
    uint r = (u + 0x7fffu + ((u >> 16) & 1u)) >> 16;
    return (ushort)r;
}
__device__ __forceinline__ float bflo(uint v) { return __uint_as_float(v << 16); }
__device__ __forceinline__ float bfhi(uint v) { return __uint_as_float(v & 0xffff0000u); }

// ---------------- CSR build ----------------

__global__ void hist_kernel(const int* __restrict__ dst, int* __restrict__ cnt, int E) {
    int e = blockIdx.x * blockDim.x + threadIdx.x;
    if (e < E) atomicAdd(&cnt[(size_t)dst[e] * CPAD], 1);
}

__global__ void scan1_kernel(const int* __restrict__ cnt, int* __restrict__ row_ptr,
                             float* __restrict__ inv_deg, int* __restrict__ blockSums, int n) {
    constexpr int T = 256, PER = 8, CHUNK = T * PER;
    __shared__ int sdata[T];
    int base = blockIdx.x * CHUNK + threadIdx.x * PER;
    int v[PER];
    int s = 0;
#pragma unroll
    for (int i = 0; i < PER; i++) {
        int idx = base + i;
        int c = (idx < n) ? cnt[(size_t)idx * CPAD] : 0;
        v[i] = c; s += c;
    }
    sdata[threadIdx.x] = s;
    __syncthreads();
    for (int off = 1; off < T; off <<= 1) {
        int x = sdata[threadIdx.x];
        int y = (threadIdx.x >= off) ? sdata[threadIdx.x - off] : 0;
        __syncthreads();
        sdata[threadIdx.x] = x + y;
        __syncthreads();
    }
    int excl = sdata[threadIdx.x] - s;
    if (threadIdx.x == T - 1) blockSums[blockIdx.x] = sdata[T - 1];
    int run = excl;
#pragma unroll
    for (int i = 0; i < PER; i++) {
        int idx = base + i;
        if (idx < n) {
            row_ptr[idx] = run;
            int d = v[i] > 1 ? v[i] : 1;
            inv_deg[idx] = 1.0f / (float)d;
        }
        run += v[i];
    }
}

__global__ void scan2_kernel(const int* __restrict__ blockSums, int* __restrict__ blockOfs,
                             int nblocks, int* __restrict__ row_ptr, int n) {
    if (threadIdx.x == 0 && blockIdx.x == 0) {
        int run = 0;
        for (int b = 0; b < nblocks; b++) {
            int t = blockSums[b];
            blockOfs[b] = run;
            run += t;
        }
        row_ptr[n] = run;
    }
}

__global__ void scan3_kernel(int* __restrict__ row_ptr, const int* __restrict__ blockOfs,
                             int* __restrict__ cursor, int n) {
    int i = blockIdx.x * blockDim.x + threadIdx.x;
    if (i < n) {
        int v = row_ptr[i] + blockOfs[i / 2048];
        row_ptr[i] = v;
        cursor[(size_t)i * CPAD] = v;
    }
}

__global__ void fill_kernel(const int* __restrict__ src, const int* __restrict__ dst,
                            int* __restrict__ cursor, int* __restrict__ col, int E) {
    int e = blockIdx.x * blockDim.x + threadIdx.x;
    if (e < E) {
        int d = dst[e];
        int pos = atomicAdd(&cursor[(size_t)d * CPAD], 1);
        col[pos] = src[e];
    }
}

// ---------------- cast fp32 -> bf16 (x input) ----------------

__global__ __launch_bounds__(256) void cast_x_kernel(const float* __restrict__ x,
                                                     ushort* __restrict__ xb, long n8) {
    long g = (long)blockIdx.x * blockDim.x + threadIdx.x;
    if (g >= n8) return;
    const float4* x4 = (const float4*)x;
    float4 a = x4[g * 2], b = x4[g * 2 + 1];
    uint4 o;
    o.x = (uint)f2bf(a.x) | ((uint)f2bf(a.y) << 16);
    o.y = (uint)f2bf(a.z) | ((uint)f2bf(a.w) << 16);
    o.z = (uint)f2bf(b.x) | ((uint)f2bf(b.y) << 16);
    o.w = (uint)f2bf(b.z) | ((uint)f2bf(b.w) << 16);
    ((uint4*)xb)[g] = o;
}

// ---------------- weight transpose+cast: BT[n][k], k<128 -> Ws, else Wn ----------------

__global__ void mk_bt_kernel(const float* __restrict__ Ws, const float* __restrict__ Wn,
                             ushort* __restrict__ BT, int FOUT) {
    int idx = blockIdx.x * blockDim.x + threadIdx.x;  // n*256 + k
    if (idx >= FOUT * 256) return;
    int n = idx >> 8, k = idx & 255;
    float v = (k < 128) ? Ws[k * FOUT + n] : Wn[(k - 128) * FOUT + n];
    BT[idx] = f2bf(v);
}

// ---------------- Aggregation: one wave per node, bf16 gather x4 unroll, fp32 accumulate ----------------

__global__ __launch_bounds__(256) void agg_kernel(const ushort* __restrict__ hb,
                                                  const int* __restrict__ row_ptr,
                                                  const int* __restrict__ col,
                                                  const float* __restrict__ inv_deg,
                                                  ushort* __restrict__ aggb, int n) {
    int node = (int)((blockIdx.x * blockDim.x + threadIdx.x) >> 6);
    int lane = threadIdx.x & 63;
    if (node >= n) return;
    const uint* h32 = (const uint*)hb;  // 64 uints per 128-feat row
    int beg = row_ptr[node], end = row_ptr[node + 1];
    float ax = 0.f, ay = 0.f, bx = 0.f, by = 0.f;
    float cx = 0.f, cy = 0.f, dx = 0.f, dy = 0.f;
    int e = beg;
    for (; e + 4 <= end; e += 4) {
        int s0 = col[e], s1 = col[e + 1], s2 = col[e + 2], s3 = col[e + 3];
        uint v0 = h32[(size_t)s0 * 64 + lane];
        uint v1 = h32[(size_t)s1 * 64 + lane];
        uint v2 = h32[(size_t)s2 * 64 + lane];
        uint v3 = h32[(size_t)s3 * 64 + lane];
        ax += bflo(v0); ay += bfhi(v0);
        bx += bflo(v1); by += bfhi(v1);
        cx += bflo(v2); cy += bfhi(v2);
        dx += bflo(v3); dy += bfhi(v3);
    }
    for (; e < end; e++) {
        uint v0 = h32[(size_t)col[e] * 64 + lane];
        ax += bflo(v0); ay += bfhi(v0);
    }
    float inv = inv_deg[node];
    float ox = ((ax + bx) + (cx + dx)) * inv;
    float oy = ((ay + by) + (cy + dy)) * inv;
    ((uint*)aggb)[(size_t)node * 64 + lane] = (uint)f2bf(ox) | ((uint)f2bf(oy) << 16);
}

// ---------------- MFMA GEMM: out[n][j] = [h|agg] @ BT^T + b ----------------

template <int FOUT, bool RELU, bool OUTBF16>
__global__ __launch_bounds__(256) void mfma_gemm(const ushort* __restrict__ hb,
                                                 const ushort* __restrict__ aggb,
                                                 const ushort* __restrict__ BTb,
                                                 const float* __restrict__ bias,
                                                 void* __restrict__ outp, int nNodes) {
    constexpr int NT = FOUT / 16;
    constexpr int BSTR = 40;
    __shared__ ushort BT[FOUT * BSTR];
    int tid = threadIdx.x;
    int wave = tid >> 6, lane = tid & 63;
    int m = lane & 15, quad = lane >> 4;
    int r0 = blockIdx.x * 64 + wave * 16;
    int arow = r0 + m;
    if (arow >= nNodes) arow = nNodes - 1;
    const ushort* hrow = hb + (size_t)arow * 128;
    const ushort* grow = aggb + (size_t)arow * 128;

    f32x4 acc[NT];
#pragma unroll
    for (int t = 0; t < NT; t++) acc[t] = (f32x4){0.f, 0.f, 0.f, 0.f};

#pragma unroll
    for (int kc = 0; kc < 8; kc++) {
        __syncthreads();
        constexpr int UNITS = FOUT * 4;  // 16B units
#pragma unroll
        for (int u0 = 0; u0 < UNITS / 256; u0++) {
            int u = tid + u0 * 256;
            int n = u >> 2, ko = (u & 3) * 8;
            short8 v = *(const short8*)(BTb + n * 256 + kc * 32 + ko);
            *(short8*)(&BT[n * BSTR + ko]) = v;
        }
        __syncthreads();
        int kg = kc * 32 + quad * 8;
        const ushort* ap = (kg < 128) ? (hrow + kg) : (grow + (kg - 128));
        short8 afrag = *(const short8*)ap;
#pragma unroll
        for (int t = 0; t < NT; t++) {
            short8 bfrag = *(const short8*)(&BT[(t * 16 + m) * BSTR + quad * 8]);
            acc[t] = __builtin_amdgcn_mfma_f32_16x16x32_bf16(afrag, bfrag, acc[t], 0, 0, 0);
        }
    }

#pragma unroll
    for (int reg = 0; reg < 4; reg++) {
        int orow = r0 + quad * 4 + reg;
        if (orow < nNodes) {
#pragma unroll
            for (int t = 0; t < NT; t++) {
                int j = t * 16 + m;
                float v = acc[t][reg] + bias[j];
                if (RELU) v = fmaxf(v, 0.f);
                if (OUTBF16)
                    ((ushort*)outp)[(size_t)orow * FOUT + j] = f2bf(v);
                else
                    ((float*)outp)[(size_t)orow * FOUT + j] = v;
            }
        }
    }
}

extern "C" void kernel_launch(void* const* d_in, const int* in_sizes, int n_in,
                              void* d_out, int out_size, void* d_ws, size_t ws_size,
                              hipStream_t stream) {
    const float* x   = (const float*)d_in[0];
    const int* src   = (const int*)d_in[1];
    const int* dst   = (const int*)d_in[2];
    const float* Ws0 = (const float*)d_in[3];
    const float* Wn0 = (const float*)d_in[4];
    const float* b0  = (const float*)d_in[5];
    const float* Ws1 = (const float*)d_in[6];
    const float* Wn1 = (const float*)d_in[7];
    const float* b1  = (const float*)d_in[8];
    const float* Ws2 = (const float*)d_in[9];
    const float* Wn2 = (const float*)d_in[10];
    const float* b2  = (const float*)d_in[11];
    float* out = (float*)d_out;

    const int N = N_NODES, E = N_EDGES;

    char* p = (char*)d_ws;
    auto take = [&](size_t bytes) {
        void* r = (void*)p;
        p += (bytes + 255) & ~(size_t)255;
        return r;
    };
    int* cnt       = (int*)take((size_t)N * CPAD * 4);  // padded; reused as CSR fill cursor
    int* row_ptr   = (int*)take((size_t)(N + 1) * 4);
    int* blockSums = (int*)take(64 * 4);
    int* blockOfs  = (int*)take(64 * 4);
    int* col       = (int*)take((size_t)E * 4);
    float* inv_deg = (float*)take((size_t)N * 4);
    ushort* xb     = (ushort*)take((size_t)N * 128 * 2);
    ushort* h1b    = (ushort*)take((size_t)N * 128 * 2);
    ushort* aggb   = (ushort*)take((size_t)N * 128 * 2);
    ushort* BT0    = (ushort*)take((size_t)128 * 256 * 2);
    ushort* BT1    = (ushort*)take((size_t)128 * 256 * 2);
    ushort* BT2    = (ushort*)take((size_t)64 * 256 * 2);

    // --- CSR build ---
    hipMemsetAsync(cnt, 0, (size_t)N * CPAD * 4, stream);
    hist_kernel<<<(E + 255) / 256, 256, 0, stream>>>(dst, cnt, E);
    int nchunks = (N + 2047) / 2048;
    scan1_kernel<<<nchunks, 256, 0, stream>>>(cnt, row_ptr, inv_deg, blockSums, N);
    scan2_kernel<<<1, 64, 0, stream>>>(blockSums, blockOfs, nchunks, row_ptr, N);
    scan3_kernel<<<(N + 255) / 256, 256, 0, stream>>>(row_ptr, blockOfs, cnt, N);
    fill_kernel<<<(E + 255) / 256, 256, 0, stream>>>(src, dst, cnt, col, E);

    // --- casts / weight transposes ---
    long n8 = (long)N * 128 / 8;
    cast_x_kernel<<<(int)((n8 + 255) / 256), 256, 0, stream>>>(x, xb, n8);
    mk_bt_kernel<<<(128 * 256 + 255) / 256, 256, 0, stream>>>(Ws0, Wn0, BT0, 128);
    mk_bt_kernel<<<(128 * 256 + 255) / 256, 256, 0, stream>>>(Ws1, Wn1, BT1, 128);
    mk_bt_kernel<<<(64 * 256 + 255) / 256, 256, 0, stream>>>(Ws2, Wn2, BT2, 64);

    int aggGrid = (int)(((long)N * 64 + 255) / 256);
    int gemmGrid = (N + 63) / 64;

    // --- layer 0: xb -> h1b ---
    agg_kernel<<<aggGrid, 256, 0, stream>>>(xb, row_ptr, col, inv_deg, aggb, N);
    mfma_gemm<128, true, true><<<gemmGrid, 256, 0, stream>>>(xb, aggb, BT0, b0, h1b, N);
    // --- layer 1: h1b -> xb (reuse) ---
    agg_kernel<<<aggGrid, 256, 0, stream>>>(h1b, row_ptr, col, inv_deg, aggb, N);
    mfma_gemm<128, true, true><<<gemmGrid, 256, 0, stream>>>(h1b, aggb, BT1, b1, xb, N);
    // --- layer 2: xb -> out (fp32) ---
    agg_kernel<<<aggGrid, 256, 0, stream>>>(xb, row_ptr, col, inv_deg, aggb, N);
    mfma_gemm<64, false, false><<<gemmGrid, 256, 0, stream>>>(xb, aggb, BT2, b2, out, N);
}

// Round 4
// 411.446 us; speedup vs baseline: 2.6539x; 1.4609x over previous
//
#include <hip/hip_runtime.h>
#include <hip/hip_bf16.h>

#define N_NODES 100000
#define N_EDGES 1600000
#define BSHIFT 8                 // 256 nodes per bucket
#define NB 391                   // ceil(100000/256)
#define BCAP 8192                // bucket capacity (mean 4092, sigma~64 -> 64 sigma headroom)

typedef __attribute__((ext_vector_type(8))) short short8;
typedef __attribute__((ext_vector_type(4))) float f32x4;
typedef unsigned short ushort;
typedef unsigned int uint;

__device__ __forceinline__ ushort f2bf(float f) {
    uint u = __float_as_uint(f);
    uint r = (u + 0x7fffu + ((u >> 16) & 1u)) >> 16;
    return (ushort)r;
}
__device__ __forceinline__ float bflo(uint v) { return __uint_as_float(v << 16); }
__device__ __forceinline__ float bfhi(uint v) { return __uint_as_float(v & 0xffff0000u); }

// ---------------- Pass A: partition edges into 391 dst-buckets ----------------
// Per block: LDS-count 4096 edges, reserve per-bucket runs with ONE global atomic
// per (block,bucket), then write packed (dlow<<17|src) words into contiguous runs.

__global__ __launch_bounds__(256) void partA_kernel(const int* __restrict__ src,
                                                    const int* __restrict__ dst,
                                                    uint* __restrict__ packed,
                                                    int* __restrict__ bucket_cnt, int E) {
    constexpr int PER = 16;  // 4096 edges/block
    __shared__ int cnt[NB];
    __shared__ int cur[NB];
    int tid = threadIdx.x;
    for (int i = tid; i < NB; i += 256) cnt[i] = 0;
    __syncthreads();
    int base = blockIdx.x * (256 * PER);
    int d[PER], s[PER];
#pragma unroll
    for (int i = 0; i < PER; i++) {
        int e = base + tid + i * 256;
        if (e < E) {
            d[i] = dst[e];
            s[i] = src[e];
            atomicAdd(&cnt[d[i] >> BSHIFT], 1);
        } else {
            d[i] = -1;
        }
    }
    __syncthreads();
    for (int i = tid; i < NB; i += 256) cur[i] = atomicAdd(&bucket_cnt[i], cnt[i]);
    __syncthreads();
#pragma unroll
    for (int i = 0; i < PER; i++) {
        if (d[i] >= 0) {
            int b = d[i] >> BSHIFT;
            int p = atomicAdd(&cur[b], 1);
            packed[(size_t)b * BCAP + p] = ((uint)(d[i] & 255) << 17) | (uint)s[i];
        }
    }
}

// ---------------- bucket offsets (exclusive scan over 391 sizes) ----------------

__global__ void bscan_kernel(const int* __restrict__ bucket_cnt, int* __restrict__ bucket_ofs) {
    if (threadIdx.x == 0 && blockIdx.x == 0) {
        int run = 0;
        for (int b = 0; b < NB; b++) {
            bucket_ofs[b] = run;
            run += bucket_cnt[b];
        }
    }
}

// ---------------- Pass B: per-bucket degrees + CSR + col fill (all LDS atomics) ----------------

__global__ __launch_bounds__(256) void partB_kernel(const uint* __restrict__ packed,
                                                    const int* __restrict__ bucket_cnt,
                                                    const int* __restrict__ bucket_ofs,
                                                    int* __restrict__ row_ptr,
                                                    float* __restrict__ inv_deg,
                                                    int* __restrict__ col, int N, int E) {
    __shared__ int deg[256];
    __shared__ int cur[256];
    __shared__ int psum[256];
    int b = blockIdx.x, tid = threadIdx.x;
    int cnt = bucket_cnt[b];
    int bofs = bucket_ofs[b];
    const uint* pk = packed + (size_t)b * BCAP;
    deg[tid] = 0;
    __syncthreads();
    // degree count (4-wide MLP, clamped loads)
    for (int e = tid; e < cnt; e += 1024) {
        uint w[4];
        int have[4];
#pragma unroll
        for (int j = 0; j < 4; j++) {
            int ee = e + j * 256;
            have[j] = ee < cnt;
            w[j] = pk[have[j] ? ee : e];
        }
#pragma unroll
        for (int j = 0; j < 4; j++)
            if (have[j]) atomicAdd(&deg[w[j] >> 17], 1);
    }
    __syncthreads();
    // exclusive scan over 256 degrees
    int d0 = deg[tid];
    psum[tid] = d0;
    __syncthreads();
    for (int off = 1; off < 256; off <<= 1) {
        int x = psum[tid];
        int y = (tid >= off) ? psum[tid - off] : 0;
        __syncthreads();
        psum[tid] = x + y;
        __syncthreads();
    }
    int excl = psum[tid] - d0;
    cur[tid] = excl;
    int g = (b << BSHIFT) + tid;
    if (g < N) {
        row_ptr[g] = bofs + excl;
        inv_deg[g] = 1.0f / (float)(d0 > 1 ? d0 : 1);
    }
    if (b == 0 && tid == 0) row_ptr[N] = E;
    __syncthreads();
    // col fill: writes confined to [bofs, bofs+cnt) -- 32KB L2-resident window
    for (int e = tid; e < cnt; e += 1024) {
        uint w[4];
        int have[4];
#pragma unroll
        for (int j = 0; j < 4; j++) {
            int ee = e + j * 256;
            have[j] = ee < cnt;
            w[j] = pk[have[j] ? ee : e];
        }
#pragma unroll
        for (int j = 0; j < 4; j++)
            if (have[j]) {
                int dl = w[j] >> 17;
                int p = atomicAdd(&cur[dl], 1);
                col[bofs + p] = (int)(w[j] & 0x1FFFFu);
            }
    }
}

// ---------------- cast fp32 -> bf16 (x input) ----------------

__global__ __launch_bounds__(256) void cast_x_kernel(const float* __restrict__ x,
                                                     ushort* __restrict__ xb, long n8) {
    long g = (long)blockIdx.x * blockDim.x + threadIdx.x;
    if (g >= n8) return;
    const float4* x4 = (const float4*)x;
    float4 a = x4[g * 2], b = x4[g * 2 + 1];
    uint4 o;
    o.x = (uint)f2bf(a.x) | ((uint)f2bf(a.y) << 16);
    o.y = (uint)f2bf(a.z) | ((uint)f2bf(a.w) << 16);
    o.z = (uint)f2bf(b.x) | ((uint)f2bf(b.y) << 16);
    o.w = (uint)f2bf(b.z) | ((uint)f2bf(b.w) << 16);
    ((uint4*)xb)[g] = o;
}

// ---------------- weight transpose+cast: BT[n][k], k<128 -> Ws, else Wn ----------------

__global__ void mk_bt_kernel(const float* __restrict__ Ws, const float* __restrict__ Wn,
                             ushort* __restrict__ BT, int FOUT) {
    int idx = blockIdx.x * blockDim.x + threadIdx.x;  // n*256 + k
    if (idx >= FOUT * 256) return;
    int n = idx >> 8, k = idx & 255;
    float v = (k < 128) ? Ws[k * FOUT + n] : Wn[(k - 128) * FOUT + n];
    BT[idx] = f2bf(v);
}

// ---------------- Aggregation: one wave/node, bf16 gather, 8 rows in flight ----------------

__global__ __launch_bounds__(256) void agg_kernel(const ushort* __restrict__ hb,
                                                  const int* __restrict__ row_ptr,
                                                  const int* __restrict__ col,
                                                  const float* __restrict__ inv_deg,
                                                  ushort* __restrict__ aggb, int n) {
    int node = (int)((blockIdx.x * blockDim.x + threadIdx.x) >> 6);
    int lane = threadIdx.x & 63;
    if (node >= n) return;
    const uint* h32 = (const uint*)hb;  // 64 uints per 128-feat row
    int beg = row_ptr[node], end = row_ptr[node + 1];
    float ax[8], ay[8];
#pragma unroll
    for (int j = 0; j < 8; j++) { ax[j] = 0.f; ay[j] = 0.f; }
    for (int e0 = beg; e0 < end; e0 += 8) {
        int rem = end - e0;  // >= 1
        uint v[8];
        int ok[8];
#pragma unroll
        for (int j = 0; j < 8; j++) {
            ok[j] = j < rem;
            int ce = e0 + (ok[j] ? j : 0);  // clamped: always a valid edge slot
            int sidx = col[ce];
            v[j] = h32[(size_t)sidx * 64 + lane];
        }
#pragma unroll
        for (int j = 0; j < 8; j++) {
            uint w = ok[j] ? v[j] : 0u;
            ax[j] += bflo(w);
            ay[j] += bfhi(w);
        }
    }
    float sx = ((ax[0] + ax[1]) + (ax[2] + ax[3])) + ((ax[4] + ax[5]) + (ax[6] + ax[7]));
    float sy = ((ay[0] + ay[1]) + (ay[2] + ay[3])) + ((ay[4] + ay[5]) + (ay[6] + ay[7]));
    float inv = inv_deg[node];
    ((uint*)aggb)[(size_t)node * 64 + lane] = (uint)f2bf(sx * inv) | ((uint)f2bf(sy * inv) << 16);
}

// ---------------- MFMA GEMM: out[n][j] = [h|agg] @ BT^T + b ----------------

template <int FOUT, bool RELU, bool OUTBF16>
__global__ __launch_bounds__(256) void mfma_gemm(const ushort* __restrict__ hb,
                                                 const ushort* __restrict__ aggb,
                                                 const ushort* __restrict__ BTb,
                                                 const float* __restrict__ bias,
                                                 void* __restrict__ outp, int nNodes) {
    constexpr int NT = FOUT / 16;
    constexpr int BSTR = 40;
    __shared__ ushort BT[FOUT * BSTR];
    int tid = threadIdx.x;
    int wave = tid >> 6, lane = tid & 63;
    int m = lane & 15, quad = lane >> 4;
    int r0 = blockIdx.x * 64 + wave * 16;
    int arow = r0 + m;
    if (arow >= nNodes) arow = nNodes - 1;
    const ushort* hrow = hb + (size_t)arow * 128;
    const ushort* grow = aggb + (size_t)arow * 128;

    f32x4 acc[NT];
#pragma unroll
    for (int t = 0; t < NT; t++) acc[t] = (f32x4){0.f, 0.f, 0.f, 0.f};

#pragma unroll
    for (int kc = 0; kc < 8; kc++) {
        __syncthreads();
        constexpr int UNITS = FOUT * 4;  // 16B units
#pragma unroll
        for (int u0 = 0; u0 < UNITS / 256; u0++) {
            int u = tid + u0 * 256;
            int n = u >> 2, ko = (u & 3) * 8;
            short8 v = *(const short8*)(BTb + n * 256 + kc * 32 + ko);
            *(short8*)(&BT[n * BSTR + ko]) = v;
        }
        __syncthreads();
        int kg = kc * 32 + quad * 8;
        const ushort* ap = (kg < 128) ? (hrow + kg) : (grow + (kg - 128));
        short8 afrag = *(const short8*)ap;
#pragma unroll
        for (int t = 0; t < NT; t++) {
            short8 bfrag = *(const short8*)(&BT[(t * 16 + m) * BSTR + quad * 8]);
            acc[t] = __builtin_amdgcn_mfma_f32_16x16x32_bf16(afrag, bfrag, acc[t], 0, 0, 0);
        }
    }

#pragma unroll
    for (int reg = 0; reg < 4; reg++) {
        int orow = r0 + quad * 4 + reg;
        if (orow < nNodes) {
#pragma unroll
            for (int t = 0; t < NT; t++) {
                int j = t * 16 + m;
                float v = acc[t][reg] + bias[j];
                if (RELU) v = fmaxf(v, 0.f);
                if (OUTBF16)
                    ((ushort*)outp)[(size_t)orow * FOUT + j] = f2bf(v);
                else
                    ((float*)outp)[(size_t)orow * FOUT + j] = v;
            }
        }
    }
}

extern "C" void kernel_launch(void* const* d_in, const int* in_sizes, int n_in,
                              void* d_out, int out_size, void* d_ws, size_t ws_size,
                              hipStream_t stream) {
    const float* x   = (const float*)d_in[0];
    const int* src   = (const int*)d_in[1];
    const int* dst   = (const int*)d_in[2];
    const float* Ws0 = (const float*)d_in[3];
    const float* Wn0 = (const float*)d_in[4];
    const float* b0  = (const float*)d_in[5];
    const float* Ws1 = (const float*)d_in[6];
    const float* Wn1 = (const float*)d_in[7];
    const float* b1  = (const float*)d_in[8];
    const float* Ws2 = (const float*)d_in[9];
    const float* Wn2 = (const float*)d_in[10];
    const float* b2  = (const float*)d_in[11];
    float* out = (float*)d_out;

    const int N = N_NODES, E = N_EDGES;

    char* p = (char*)d_ws;
    auto take = [&](size_t bytes) {
        void* r = (void*)p;
        p += (bytes + 255) & ~(size_t)255;
        return r;
    };
    uint* packed    = (uint*)take((size_t)NB * BCAP * 4);  // 12.8 MB
    int* bucket_cnt = (int*)take((size_t)NB * 4);
    int* bucket_ofs = (int*)take((size_t)NB * 4);
    int* row_ptr    = (int*)take((size_t)(N + 1) * 4);
    int* col        = (int*)take((size_t)E * 4);
    float* inv_deg  = (float*)take((size_t)N * 4);
    ushort* xb      = (ushort*)take((size_t)N * 128 * 2);
    ushort* h1b     = (ushort*)take((size_t)N * 128 * 2);
    ushort* aggb    = (ushort*)take((size_t)N * 128 * 2);
    ushort* BT0     = (ushort*)take((size_t)128 * 256 * 2);
    ushort* BT1     = (ushort*)take((size_t)128 * 256 * 2);
    ushort* BT2     = (ushort*)take((size_t)64 * 256 * 2);

    // --- CSR build via bucketed partition ---
    hipMemsetAsync(bucket_cnt, 0, (size_t)NB * 4, stream);
    int nblkA = (E + 4096 - 1) / 4096;
    partA_kernel<<<nblkA, 256, 0, stream>>>(src, dst, packed, bucket_cnt, E);
    bscan_kernel<<<1, 64, 0, stream>>>(bucket_cnt, bucket_ofs);
    partB_kernel<<<NB, 256, 0, stream>>>(packed, bucket_cnt, bucket_ofs, row_ptr, inv_deg, col, N, E);

    // --- casts / weight transposes ---
    long n8 = (long)N * 128 / 8;
    cast_x_kernel<<<(int)((n8 + 255) / 256), 256, 0, stream>>>(x, xb, n8);
    mk_bt_kernel<<<(128 * 256 + 255) / 256, 256, 0, stream>>>(Ws0, Wn0, BT0, 128);
    mk_bt_kernel<<<(128 * 256 + 255) / 256, 256, 0, stream>>>(Ws1, Wn1, BT1, 128);
    mk_bt_kernel<<<(64 * 256 + 255) / 256, 256, 0, stream>>>(Ws2, Wn2, BT2, 64);

    int aggGrid = (int)(((long)N * 64 + 255) / 256);
    int gemmGrid = (N + 63) / 64;

    // --- layer 0: xb -> h1b ---
    agg_kernel<<<aggGrid, 256, 0, stream>>>(xb, row_ptr, col, inv_deg, aggb, N);
    mfma_gemm<128, true, true><<<gemmGrid, 256, 0, stream>>>(xb, aggb, BT0, b0, h1b, N);
    // --- layer 1: h1b -> xb (reuse) ---
    agg_kernel<<<aggGrid, 256, 0, stream>>>(h1b, row_ptr, col, inv_deg, aggb, N);
    mfma_gemm<128, true, true><<<gemmGrid, 256, 0, stream>>>(h1b, aggb, BT1, b1, xb, N);
    // --- layer 2: xb -> out (fp32) ---
    agg_kernel<<<aggGrid, 256, 0, stream>>>(xb, row_ptr, col, inv_deg, aggb, N);
    mfma_gemm<64, false, false><<<gemmGrid, 256, 0, stream>>>(xb, aggb, BT2, b2, out, N);
}

// Round 5
// 402.431 us; speedup vs baseline: 2.7133x; 1.0224x over previous
//
#include <hip/hip_runtime.h>
#include <hip/hip_bf16.h>

#define N_NODES 100000
#define N_EDGES 1600000
#define BSHIFT 8                 // 256 nodes per bucket
#define NB 391                   // ceil(100000/256)
#define BCAP 8192                // bucket capacity (mean 4092 -> huge headroom)

typedef __attribute__((ext_vector_type(8))) short short8;
typedef __attribute__((ext_vector_type(4))) float f32x4;
typedef unsigned short ushort;
typedef unsigned int uint;

__device__ __forceinline__ ushort f2bf(float f) {
    uint u = __float_as_uint(f);
    uint r = (u + 0x7fffu + ((u >> 16) & 1u)) >> 16;
    return (ushort)r;
}
__device__ __forceinline__ float bflo(uint v) { return __uint_as_float(v << 16); }
__device__ __forceinline__ float bfhi(uint v) { return __uint_as_float(v & 0xffff0000u); }

// ---------------- Pass A: partition edges into 391 dst-buckets ----------------

__global__ __launch_bounds__(256) void partA_kernel(const int* __restrict__ src,
                                                    const int* __restrict__ dst,
                                                    uint* __restrict__ packed,
                                                    int* __restrict__ bucket_cnt, int E) {
    constexpr int PER = 16;  // 4096 edges/block
    __shared__ int cnt[NB];
    __shared__ int cur[NB];
    int tid = threadIdx.x;
    for (int i = tid; i < NB; i += 256) cnt[i] = 0;
    __syncthreads();
    int base = blockIdx.x * (256 * PER);
    int d[PER], s[PER];
#pragma unroll
    for (int i = 0; i < PER; i++) {
        int e = base + tid + i * 256;
        if (e < E) {
            d[i] = dst[e];
            s[i] = src[e];
            atomicAdd(&cnt[d[i] >> BSHIFT], 1);
        } else {
            d[i] = -1;
        }
    }
    __syncthreads();
    for (int i = tid; i < NB; i += 256) cur[i] = atomicAdd(&bucket_cnt[i], cnt[i]);
    __syncthreads();
#pragma unroll
    for (int i = 0; i < PER; i++) {
        if (d[i] >= 0) {
            int b = d[i] >> BSHIFT;
            int p = atomicAdd(&cur[b], 1);
            packed[(size_t)b * BCAP + p] = ((uint)(d[i] & 255) << 17) | (uint)s[i];
        }
    }
}

// ---------------- bucket offsets: one-block LDS exclusive scan ----------------

__global__ __launch_bounds__(512) void bscan_kernel(const int* __restrict__ bucket_cnt,
                                                    int* __restrict__ bucket_ofs) {
    __shared__ int s[512];
    int tid = threadIdx.x;
    int v = (tid < NB) ? bucket_cnt[tid] : 0;
    s[tid] = v;
    __syncthreads();
    for (int off = 1; off < 512; off <<= 1) {
        int x = s[tid];
        int y = (tid >= off) ? s[tid - off] : 0;
        __syncthreads();
        s[tid] = x + y;
        __syncthreads();
    }
    if (tid < NB) bucket_ofs[tid] = s[tid] - v;
}

// ---------------- Pass B: per-bucket degrees + CSR + col fill (LDS atomics) ----------------

__global__ __launch_bounds__(256) void partB_kernel(const uint* __restrict__ packed,
                                                    const int* __restrict__ bucket_cnt,
                                                    const int* __restrict__ bucket_ofs,
                                                    int* __restrict__ row_ptr,
                                                    float* __restrict__ inv_deg,
                                                    int* __restrict__ col, int N, int E) {
    __shared__ int deg[256];
    __shared__ int cur[256];
    __shared__ int psum[256];
    int b = blockIdx.x, tid = threadIdx.x;
    int cnt = bucket_cnt[b];
    int bofs = bucket_ofs[b];
    const uint* pk = packed + (size_t)b * BCAP;
    deg[tid] = 0;
    __syncthreads();
    for (int e = tid; e < cnt; e += 1024) {
        uint w[4];
        int have[4];
#pragma unroll
        for (int j = 0; j < 4; j++) {
            int ee = e + j * 256;
            have[j] = ee < cnt;
            w[j] = pk[have[j] ? ee : e];
        }
#pragma unroll
        for (int j = 0; j < 4; j++)
            if (have[j]) atomicAdd(&deg[w[j] >> 17], 1);
    }
    __syncthreads();
    int d0 = deg[tid];
    psum[tid] = d0;
    __syncthreads();
    for (int off = 1; off < 256; off <<= 1) {
        int x = psum[tid];
        int y = (tid >= off) ? psum[tid - off] : 0;
        __syncthreads();
        psum[tid] = x + y;
        __syncthreads();
    }
    int excl = psum[tid] - d0;
    cur[tid] = excl;
    int g = (b << BSHIFT) + tid;
    if (g < N) {
        row_ptr[g] = bofs + excl;
        inv_deg[g] = 1.0f / (float)(d0 > 1 ? d0 : 1);
    }
    if (b == 0 && tid == 0) row_ptr[N] = E;
    __syncthreads();
    for (int e = tid; e < cnt; e += 1024) {
        uint w[4];
        int have[4];
#pragma unroll
        for (int j = 0; j < 4; j++) {
            int ee = e + j * 256;
            have[j] = ee < cnt;
            w[j] = pk[have[j] ? ee : e];
        }
#pragma unroll
        for (int j = 0; j < 4; j++)
            if (have[j]) {
                int dl = w[j] >> 17;
                int p = atomicAdd(&cur[dl], 1);
                col[bofs + p] = (int)(w[j] & 0x1FFFFu);
            }
    }
}

// ---------------- cast fp32 -> bf16 (x input) ----------------

__global__ __launch_bounds__(256) void cast_x_kernel(const float* __restrict__ x,
                                                     ushort* __restrict__ xb, long n8) {
    long g = (long)blockIdx.x * blockDim.x + threadIdx.x;
    if (g >= n8) return;
    const float4* x4 = (const float4*)x;
    float4 a = x4[g * 2], b = x4[g * 2 + 1];
    uint4 o;
    o.x = (uint)f2bf(a.x) | ((uint)f2bf(a.y) << 16);
    o.y = (uint)f2bf(a.z) | ((uint)f2bf(a.w) << 16);
    o.z = (uint)f2bf(b.x) | ((uint)f2bf(b.y) << 16);
    o.w = (uint)f2bf(b.z) | ((uint)f2bf(b.w) << 16);
    ((uint4*)xb)[g] = o;
}

// ---------------- weight transpose+cast: BT[n][k], k<128 -> Ws, else Wn ----------------

__global__ void mk_bt_kernel(const float* __restrict__ Ws, const float* __restrict__ Wn,
                             ushort* __restrict__ BT, int FOUT) {
    int idx = blockIdx.x * blockDim.x + threadIdx.x;  // n*256 + k
    if (idx >= FOUT * 256) return;
    int n = idx >> 8, k = idx & 255;
    float v = (k < 128) ? Ws[k * FOUT + n] : Wn[(k - 128) * FOUT + n];
    BT[idx] = f2bf(v);
}

// ---------------- Aggregation: one wave/node; dwordx4 gather = 4 rows per VMEM instr ----------------
// lane = (quad, sub): quad=lane>>4 picks edge within group-of-4, sub=lane&15 picks 16B chunk.
// Each lane accumulates 8 features [sub*8..sub*8+8); cross-quad shfl_xor reduce at end.

__global__ __launch_bounds__(256) void agg_kernel(const ushort* __restrict__ hb,
                                                  const int* __restrict__ row_ptr,
                                                  const int* __restrict__ col,
                                                  const float* __restrict__ inv_deg,
                                                  ushort* __restrict__ aggb, int n) {
    int node = (int)((blockIdx.x * blockDim.x + threadIdx.x) >> 6);
    int lane = threadIdx.x & 63;
    if (node >= n) return;
    int quad = lane >> 4;
    int sub = lane & 15;
    const char* hbase = (const char*)hb;
    int beg = row_ptr[node], end = row_ptr[node + 1];
    float acc[8];
#pragma unroll
    for (int j = 0; j < 8; j++) acc[j] = 0.f;
    int suboff = sub * 16;
    for (int e0 = beg; e0 < end; e0 += 8) {
        int rem = end - e0;
        int i0 = quad, i1 = quad + 4;
        float m0 = (i0 < rem) ? 1.f : 0.f;
        float m1 = (i1 < rem) ? 1.f : 0.f;
        int e0c = e0 + ((i0 < rem) ? i0 : 0);
        int e1c = e0 + ((i1 < rem) ? i1 : 0);
        int s0 = col[e0c], s1 = col[e1c];
        uint4 v0 = *(const uint4*)(hbase + (((uint)s0 << 8) + suboff));
        uint4 v1 = *(const uint4*)(hbase + (((uint)s1 << 8) + suboff));
        acc[0] += bflo(v0.x) * m0; acc[1] += bfhi(v0.x) * m0;
        acc[2] += bflo(v0.y) * m0; acc[3] += bfhi(v0.y) * m0;
        acc[4] += bflo(v0.z) * m0; acc[5] += bfhi(v0.z) * m0;
        acc[6] += bflo(v0.w) * m0; acc[7] += bfhi(v0.w) * m0;
        acc[0] += bflo(v1.x) * m1; acc[1] += bfhi(v1.x) * m1;
        acc[2] += bflo(v1.y) * m1; acc[3] += bfhi(v1.y) * m1;
        acc[4] += bflo(v1.z) * m1; acc[5] += bfhi(v1.z) * m1;
        acc[6] += bflo(v1.w) * m1; acc[7] += bfhi(v1.w) * m1;
    }
    // reduce across quads (lane bits 4,5)
#pragma unroll
    for (int j = 0; j < 8; j++) {
        acc[j] += __shfl_xor(acc[j], 16);
        acc[j] += __shfl_xor(acc[j], 32);
    }
    if (quad == 0) {
        float inv = inv_deg[node];
        uint4 o;
        o.x = (uint)f2bf(acc[0] * inv) | ((uint)f2bf(acc[1] * inv) << 16);
        o.y = (uint)f2bf(acc[2] * inv) | ((uint)f2bf(acc[3] * inv) << 16);
        o.z = (uint)f2bf(acc[4] * inv) | ((uint)f2bf(acc[5] * inv) << 16);
        o.w = (uint)f2bf(acc[6] * inv) | ((uint)f2bf(acc[7] * inv) << 16);
        *(uint4*)((char*)aggb + (size_t)node * 256 + suboff) = o;
    }
}

// ---------------- MFMA GEMM: out[n][j] = [h|agg] @ BT^T + b ----------------

template <int FOUT, bool RELU, bool OUTBF16>
__global__ __launch_bounds__(256) void mfma_gemm(const ushort* __restrict__ hb,
                                                 const ushort* __restrict__ aggb,
                                                 const ushort* __restrict__ BTb,
                                                 const float* __restrict__ bias,
                                                 void* __restrict__ outp, int nNodes) {
    constexpr int NT = FOUT / 16;
    constexpr int BSTR = 40;
    __shared__ ushort BT[FOUT * BSTR];
    int tid = threadIdx.x;
    int wave = tid >> 6, lane = tid & 63;
    int m = lane & 15, quad = lane >> 4;
    int r0 = blockIdx.x * 64 + wave * 16;
    int arow = r0 + m;
    if (arow >= nNodes) arow = nNodes - 1;
    const ushort* hrow = hb + (size_t)arow * 128;
    const ushort* grow = aggb + (size_t)arow * 128;

    f32x4 acc[NT];
#pragma unroll
    for (int t = 0; t < NT; t++) acc[t] = (f32x4){0.f, 0.f, 0.f, 0.f};

#pragma unroll
    for (int kc = 0; kc < 8; kc++) {
        __syncthreads();
        constexpr int UNITS = FOUT * 4;  // 16B units
#pragma unroll
        for (int u0 = 0; u0 < UNITS / 256; u0++) {
            int u = tid + u0 * 256;
            int n = u >> 2, ko = (u & 3) * 8;
            short8 v = *(const short8*)(BTb + n * 256 + kc * 32 + ko);
            *(short8*)(&BT[n * BSTR + ko]) = v;
        }
        __syncthreads();
        int kg = kc * 32 + quad * 8;
        const ushort* ap = (kg < 128) ? (hrow + kg) : (grow + (kg - 128));
        short8 afrag = *(const short8*)ap;
#pragma unroll
        for (int t = 0; t < NT; t++) {
            short8 bfrag = *(const short8*)(&BT[(t * 16 + m) * BSTR + quad * 8]);
            acc[t] = __builtin_amdgcn_mfma_f32_16x16x32_bf16(afrag, bfrag, acc[t], 0, 0, 0);
        }
    }

#pragma unroll
    for (int reg = 0; reg < 4; reg++) {
        int orow = r0 + quad * 4 + reg;
        if (orow < nNodes) {
#pragma unroll
            for (int t = 0; t < NT; t++) {
                int j = t * 16 + m;
                float v = acc[t][reg] + bias[j];
                if (RELU) v = fmaxf(v, 0.f);
                if (OUTBF16)
                    ((ushort*)outp)[(size_t)orow * FOUT + j] = f2bf(v);
                else
                    ((float*)outp)[(size_t)orow * FOUT + j] = v;
            }
        }
    }
}

extern "C" void kernel_launch(void* const* d_in, const int* in_sizes, int n_in,
                              void* d_out, int out_size, void* d_ws, size_t ws_size,
                              hipStream_t stream) {
    const float* x   = (const float*)d_in[0];
    const int* src   = (const int*)d_in[1];
    const int* dst   = (const int*)d_in[2];
    const float* Ws0 = (const float*)d_in[3];
    const float* Wn0 = (const float*)d_in[4];
    const float* b0  = (const float*)d_in[5];
    const float* Ws1 = (const float*)d_in[6];
    const float* Wn1 = (const float*)d_in[7];
    const float* b1  = (const float*)d_in[8];
    const float* Ws2 = (const float*)d_in[9];
    const float* Wn2 = (const float*)d_in[10];
    const float* b2  = (const float*)d_in[11];
    float* out = (float*)d_out;

    const int N = N_NODES, E = N_EDGES;

    char* p = (char*)d_ws;
    auto take = [&](size_t bytes) {
        void* r = (void*)p;
        p += (bytes + 255) & ~(size_t)255;
        return r;
    };
    uint* packed    = (uint*)take((size_t)NB * BCAP * 4);  // 12.8 MB
    int* bucket_cnt = (int*)take((size_t)NB * 4);
    int* bucket_ofs = (int*)take((size_t)NB * 4);
    int* row_ptr    = (int*)take((size_t)(N + 1) * 4);
    int* col        = (int*)take((size_t)E * 4);
    float* inv_deg  = (float*)take((size_t)N * 4);
    ushort* xb      = (ushort*)take((size_t)N * 128 * 2);
    ushort* h1b     = (ushort*)take((size_t)N * 128 * 2);
    ushort* aggb    = (ushort*)take((size_t)N * 128 * 2);
    ushort* BT0     = (ushort*)take((size_t)128 * 256 * 2);
    ushort* BT1     = (ushort*)take((size_t)128 * 256 * 2);
    ushort* BT2     = (ushort*)take((size_t)64 * 256 * 2);

    // --- CSR build via bucketed partition ---
    hipMemsetAsync(bucket_cnt, 0, (size_t)NB * 4, stream);
    int nblkA = (E + 4096 - 1) / 4096;
    partA_kernel<<<nblkA, 256, 0, stream>>>(src, dst, packed, bucket_cnt, E);
    bscan_kernel<<<1, 512, 0, stream>>>(bucket_cnt, bucket_ofs);
    partB_kernel<<<NB, 256, 0, stream>>>(packed, bucket_cnt, bucket_ofs, row_ptr, inv_deg, col, N, E);

    // --- casts / weight transposes ---
    long n8 = (long)N * 128 / 8;
    cast_x_kernel<<<(int)((n8 + 255) / 256), 256, 0, stream>>>(x, xb, n8);
    mk_bt_kernel<<<(128 * 256 + 255) / 256, 256, 0, stream>>>(Ws0, Wn0, BT0, 128);
    mk_bt_kernel<<<(128 * 256 + 255) / 256, 256, 0, stream>>>(Ws1, Wn1, BT1, 128);
    mk_bt_kernel<<<(64 * 256 + 255) / 256, 256, 0, stream>>>(Ws2, Wn2, BT2, 64);

    int aggGrid = (int)(((long)N * 64 + 255) / 256);
    int gemmGrid = (N + 63) / 64;

    // --- layer 0: xb -> h1b ---
    agg_kernel<<<aggGrid, 256, 0, stream>>>(xb, row_ptr, col, inv_deg, aggb, N);
    mfma_gemm<128, true, true><<<gemmGrid, 256, 0, stream>>>(xb, aggb, BT0, b0, h1b, N);
    // --- layer 1: h1b -> xb (reuse) ---
    agg_kernel<<<aggGrid, 256, 0, stream>>>(h1b, row_ptr, col, inv_deg, aggb, N);
    mfma_gemm<128, true, true><<<gemmGrid, 256, 0, stream>>>(h1b, aggb, BT1, b1, xb, N);
    // --- layer 2: xb -> out (fp32) ---
    agg_kernel<<<aggGrid, 256, 0, stream>>>(xb, row_ptr, col, inv_deg, aggb, N);
    mfma_gemm<64, false, false><<<gemmGrid, 256, 0, stream>>>(xb, aggb, BT2, b2, out, N);
}

// Round 7
// 389.810 us; speedup vs baseline: 2.8012x; 1.0324x over previous
//
#include <hip/hip_runtime.h>
#include <hip/hip_bf16.h>

#define N_NODES 100000
#define N_EDGES 1600000
#define BSHIFT 8                 // 256 nodes per bucket
#define NB 391                   // ceil(100000/256)
#define BCAP 8192                // bucket capacity (mean 4092 -> huge headroom)

typedef __attribute__((ext_vector_type(8))) short short8;
typedef __attribute__((ext_vector_type(4))) float f32x4;
typedef unsigned short ushort;
typedef unsigned int uint;

__device__ __forceinline__ ushort f2bf(float f) {
    uint u = __float_as_uint(f);
    uint r = (u + 0x7fffu + ((u >> 16) & 1u)) >> 16;
    return (ushort)r;
}
__device__ __forceinline__ float bflo(uint v) { return __uint_as_float(v << 16); }
__device__ __forceinline__ float bfhi(uint v) { return __uint_as_float(v & 0xffff0000u); }

// ---------------- Pass A: partition edges into 391 dst-buckets ----------------

__global__ __launch_bounds__(256) void partA_kernel(const int* __restrict__ src,
                                                    const int* __restrict__ dst,
                                                    uint* __restrict__ packed,
                                                    int* __restrict__ bucket_cnt, int E) {
    constexpr int PER = 16;  // 4096 edges/block
    __shared__ int cnt[NB];
    __shared__ int cur[NB];
    int tid = threadIdx.x;
    for (int i = tid; i < NB; i += 256) cnt[i] = 0;
    __syncthreads();
    int base = blockIdx.x * (256 * PER);
    int d[PER], s[PER];
#pragma unroll
    for (int i = 0; i < PER; i++) {
        int e = base + tid + i * 256;
        if (e < E) {
            d[i] = dst[e];
            s[i] = src[e];
            atomicAdd(&cnt[d[i] >> BSHIFT], 1);
        } else {
            d[i] = -1;
        }
    }
    __syncthreads();
    for (int i = tid; i < NB; i += 256) cur[i] = atomicAdd(&bucket_cnt[i], cnt[i]);
    __syncthreads();
#pragma unroll
    for (int i = 0; i < PER; i++) {
        if (d[i] >= 0) {
            int b = d[i] >> BSHIFT;
            int p = atomicAdd(&cur[b], 1);
            packed[(size_t)b * BCAP + p] = ((uint)(d[i] & 255) << 17) | (uint)s[i];
        }
    }
}

// ---------------- Pass B: per-bucket prefix + degrees + CSR + col fill ----------------

__global__ __launch_bounds__(256) void partB_kernel(const uint* __restrict__ packed,
                                                    const int* __restrict__ bucket_cnt,
                                                    int* __restrict__ row_ptr,
                                                    float* __restrict__ inv_deg,
                                                    int* __restrict__ col, int N, int E) {
    __shared__ int deg[256];
    __shared__ int cur[256];
    __shared__ int psum[256];
    __shared__ int sofs;
    int b = blockIdx.x, tid = threadIdx.x;
    int cnt = bucket_cnt[b];
    // bucket offset: parallel sum of bucket_cnt[0..b)
    {
        int part = 0;
        for (int i = tid; i < b; i += 256) part += bucket_cnt[i];
        psum[tid] = part;
        __syncthreads();
        for (int off = 128; off > 0; off >>= 1) {
            if (tid < off) psum[tid] += psum[tid + off];
            __syncthreads();
        }
        if (tid == 0) sofs = psum[0];
        __syncthreads();
    }
    int bofs = sofs;
    const uint* pk = packed + (size_t)b * BCAP;
    deg[tid] = 0;
    __syncthreads();
    for (int e = tid; e < cnt; e += 1024) {
        uint w[4];
        int have[4];
#pragma unroll
        for (int j = 0; j < 4; j++) {
            int ee = e + j * 256;
            have[j] = ee < cnt;
            w[j] = pk[have[j] ? ee : e];
        }
#pragma unroll
        for (int j = 0; j < 4; j++)
            if (have[j]) atomicAdd(&deg[w[j] >> 17], 1);
    }
    __syncthreads();
    int d0 = deg[tid];
    psum[tid] = d0;
    __syncthreads();
    for (int off = 1; off < 256; off <<= 1) {
        int x = psum[tid];
        int y = (tid >= off) ? psum[tid - off] : 0;
        __syncthreads();
        psum[tid] = x + y;
        __syncthreads();
    }
    int excl = psum[tid] - d0;
    cur[tid] = excl;
    int g = (b << BSHIFT) + tid;
    if (g < N) {
        row_ptr[g] = bofs + excl;
        inv_deg[g] = 1.0f / (float)(d0 > 1 ? d0 : 1);
    }
    if (b == 0 && tid == 0) row_ptr[N] = E;
    __syncthreads();
    for (int e = tid; e < cnt; e += 1024) {
        uint w[4];
        int have[4];
#pragma unroll
        for (int j = 0; j < 4; j++) {
            int ee = e + j * 256;
            have[j] = ee < cnt;
            w[j] = pk[have[j] ? ee : e];
        }
#pragma unroll
        for (int j = 0; j < 4; j++)
            if (have[j]) {
                int dl = w[j] >> 17;
                int p = atomicAdd(&cur[dl], 1);
                col[bofs + p] = (int)(w[j] & 0x1FFFFu);
            }
    }
}

// ---------------- prep: cast x -> bf16  AND  transpose+cast all 3 weight pairs ----------------
// x cast: n8 = 100000*128/8 = 1,600,000 8-float units; 256 units/block -> 6250 blocks.

#define CAST_BLK 6250

__global__ __launch_bounds__(256) void prep_kernel(const float* __restrict__ x,
                                                   ushort* __restrict__ xb,
                                                   const float* __restrict__ Ws0,
                                                   const float* __restrict__ Wn0,
                                                   const float* __restrict__ Ws1,
                                                   const float* __restrict__ Wn1,
                                                   const float* __restrict__ Ws2,
                                                   const float* __restrict__ Wn2,
                                                   ushort* __restrict__ BT0,
                                                   ushort* __restrict__ BT1,
                                                   ushort* __restrict__ BT2) {
    int blk = blockIdx.x;
    if (blk < CAST_BLK) {
        long n8 = (long)N_NODES * 128 / 8;
        long g = (long)blk * 256 + threadIdx.x;
        if (g >= n8) return;
        const float4* x4 = (const float4*)x;
        float4 a = x4[g * 2], b = x4[g * 2 + 1];
        uint4 o;
        o.x = (uint)f2bf(a.x) | ((uint)f2bf(a.y) << 16);
        o.y = (uint)f2bf(a.z) | ((uint)f2bf(a.w) << 16);
        o.z = (uint)f2bf(b.x) | ((uint)f2bf(b.y) << 16);
        o.w = (uint)f2bf(b.z) | ((uint)f2bf(b.w) << 16);
        ((uint4*)xb)[g] = o;
        return;
    }
    int idx = (blk - CAST_BLK) * 256 + threadIdx.x;  // covers 320 blocks = 81920
    const float* Ws;
    const float* Wn;
    ushort* BT;
    int FOUT;
    if (idx < 128 * 256) {
        Ws = Ws0; Wn = Wn0; BT = BT0; FOUT = 128;
    } else if (idx < 2 * 128 * 256) {
        idx -= 128 * 256;
        Ws = Ws1; Wn = Wn1; BT = BT1; FOUT = 128;
    } else if (idx < 2 * 128 * 256 + 64 * 256) {
        idx -= 2 * 128 * 256;
        Ws = Ws2; Wn = Wn2; BT = BT2; FOUT = 64;
    } else {
        return;
    }
    int n = idx >> 8, k = idx & 255;
    float v = (k < 128) ? Ws[k * FOUT + n] : Wn[(k - 128) * FOUT + n];
    BT[idx] = f2bf(v);
}

// ---------------- Aggregation: one wave/node; 16 edges / 4 dwordx4 gathers in flight ----------------

__global__ __launch_bounds__(256) void agg_kernel(const ushort* __restrict__ hb,
                                                  const int* __restrict__ row_ptr,
                                                  const int* __restrict__ col,
                                                  const float* __restrict__ inv_deg,
                                                  ushort* __restrict__ aggb, int n) {
    int node = (int)((blockIdx.x * blockDim.x + threadIdx.x) >> 6);
    int lane = threadIdx.x & 63;
    if (node >= n) return;
    int quad = lane >> 4;
    int sub = lane & 15;
    const char* hbase = (const char*)hb;
    int beg = row_ptr[node], end = row_ptr[node + 1];
    float acc[8];
#pragma unroll
    for (int j = 0; j < 8; j++) acc[j] = 0.f;
    int suboff = sub * 16;
    for (int e0 = beg; e0 < end; e0 += 16) {
        int rem = end - e0;
        int idxv[4];
        float msk[4];
#pragma unroll
        for (int j = 0; j < 4; j++) {
            int i = quad + 4 * j;
            msk[j] = (i < rem) ? 1.f : 0.f;
            idxv[j] = col[e0 + ((i < rem) ? i : 0)];
        }
        uint4 v[4];
#pragma unroll
        for (int j = 0; j < 4; j++)
            v[j] = *(const uint4*)(hbase + (((uint)idxv[j] << 8) + suboff));
#pragma unroll
        for (int j = 0; j < 4; j++) {
            acc[0] += bflo(v[j].x) * msk[j]; acc[1] += bfhi(v[j].x) * msk[j];
            acc[2] += bflo(v[j].y) * msk[j]; acc[3] += bfhi(v[j].y) * msk[j];
            acc[4] += bflo(v[j].z) * msk[j]; acc[5] += bfhi(v[j].z) * msk[j];
            acc[6] += bflo(v[j].w) * msk[j]; acc[7] += bfhi(v[j].w) * msk[j];
        }
    }
    // reduce across quads (lane bits 4,5)
#pragma unroll
    for (int j = 0; j < 8; j++) {
        acc[j] += __shfl_xor(acc[j], 16);
        acc[j] += __shfl_xor(acc[j], 32);
    }
    if (quad == 0) {
        float inv = inv_deg[node];
        uint4 o;
        o.x = (uint)f2bf(acc[0] * inv) | ((uint)f2bf(acc[1] * inv) << 16);
        o.y = (uint)f2bf(acc[2] * inv) | ((uint)f2bf(acc[3] * inv) << 16);
        o.z = (uint)f2bf(acc[4] * inv) | ((uint)f2bf(acc[5] * inv) << 16);
        o.w = (uint)f2bf(acc[6] * inv) | ((uint)f2bf(acc[7] * inv) << 16);
        *(uint4*)((char*)aggb + (size_t)node * 256 + suboff) = o;
    }
}

// ---------------- MFMA GEMM: out[n][j] = [h|agg] @ BT^T + b ----------------

template <int FOUT, bool RELU, bool OUTBF16>
__global__ __launch_bounds__(256) void mfma_gemm(const ushort* __restrict__ hb,
                                                 const ushort* __restrict__ aggb,
                                                 const ushort* __restrict__ BTb,
                                                 const float* __restrict__ bias,
                                                 void* __restrict__ outp, int nNodes) {
    constexpr int NT = FOUT / 16;
    constexpr int BSTR = 40;
    __shared__ ushort BT[FOUT * BSTR];
    int tid = threadIdx.x;
    int wave = tid >> 6, lane = tid & 63;
    int m = lane & 15, quad = lane >> 4;
    int r0 = blockIdx.x * 64 + wave * 16;
    int arow = r0 + m;
    if (arow >= nNodes) arow = nNodes - 1;
    const ushort* hrow = hb + (size_t)arow * 128;
    const ushort* grow = aggb + (size_t)arow * 128;

    f32x4 acc[NT];
#pragma unroll
    for (int t = 0; t < NT; t++) acc[t] = (f32x4){0.f, 0.f, 0.f, 0.f};

#pragma unroll
    for (int kc = 0; kc < 8; kc++) {
        __syncthreads();
        constexpr int UNITS = FOUT * 4;  // 16B units
#pragma unroll
        for (int u0 = 0; u0 < UNITS / 256; u0++) {
            int u = tid + u0 * 256;
            int n = u >> 2, ko = (u & 3) * 8;
            short8 v = *(const short8*)(BTb + n * 256 + kc * 32 + ko);
            *(short8*)(&BT[n * BSTR + ko]) = v;
        }
        __syncthreads();
        int kg = kc * 32 + quad * 8;
        const ushort* ap = (kg < 128) ? (hrow + kg) : (grow + (kg - 128));
        short8 afrag = *(const short8*)ap;
#pragma unroll
        for (int t = 0; t < NT; t++) {
            short8 bfrag = *(const short8*)(&BT[(t * 16 + m) * BSTR + quad * 8]);
            acc[t] = __builtin_amdgcn_mfma_f32_16x16x32_bf16(afrag, bfrag, acc[t], 0, 0, 0);
        }
    }

#pragma unroll
    for (int reg = 0; reg < 4; reg++) {
        int orow = r0 + quad * 4 + reg;
        if (orow < nNodes) {
#pragma unroll
            for (int t = 0; t < NT; t++) {
                int j = t * 16 + m;
                float v = acc[t][reg] + bias[j];
                if (RELU) v = fmaxf(v, 0.f);
                if (OUTBF16)
                    ((ushort*)outp)[(size_t)orow * FOUT + j] = f2bf(v);
                else
                    ((float*)outp)[(size_t)orow * FOUT + j] = v;
            }
        }
    }
}

extern "C" void kernel_launch(void* const* d_in, const int* in_sizes, int n_in,
                              void* d_out, int out_size, void* d_ws, size_t ws_size,
                              hipStream_t stream) {
    const float* x   = (const float*)d_in[0];
    const int* src   = (const int*)d_in[1];
    const int* dst   = (const int*)d_in[2];
    const float* Ws0 = (const float*)d_in[3];
    const float* Wn0 = (const float*)d_in[4];
    const float* b0  = (const float*)d_in[5];
    const float* Ws1 = (const float*)d_in[6];
    const float* Wn1 = (const float*)d_in[7];
    const float* b1  = (const float*)d_in[8];
    const float* Ws2 = (const float*)d_in[9];
    const float* Wn2 = (const float*)d_in[10];
    const float* b2  = (const float*)d_in[11];
    float* out = (float*)d_out;

    const int N = N_NODES, E = N_EDGES;

    char* p = (char*)d_ws;
    auto take = [&](size_t bytes) {
        void* r = (void*)p;
        p += (bytes + 255) & ~(size_t)255;
        return r;
    };
    uint* packed    = (uint*)take((size_t)NB * BCAP * 4);  // 12.8 MB
    int* bucket_cnt = (int*)take((size_t)NB * 4);
    int* row_ptr    = (int*)take((size_t)(N + 1) * 4);
    int* col        = (int*)take((size_t)E * 4);
    float* inv_deg  = (float*)take((size_t)N * 4);
    ushort* xb      = (ushort*)take((size_t)N * 128 * 2);
    ushort* h1b     = (ushort*)take((size_t)N * 128 * 2);
    ushort* aggb    = (ushort*)take((size_t)N * 128 * 2);
    ushort* BT0     = (ushort*)take((size_t)128 * 256 * 2);
    ushort* BT1     = (ushort*)take((size_t)128 * 256 * 2);
    ushort* BT2     = (ushort*)take((size_t)64 * 256 * 2);

    // --- CSR build via bucketed partition ---
    hipMemsetAsync(bucket_cnt, 0, (size_t)NB * 4, stream);
    int nblkA = (E + 4096 - 1) / 4096;
    partA_kernel<<<nblkA, 256, 0, stream>>>(src, dst, packed, bucket_cnt, E);
    partB_kernel<<<NB, 256, 0, stream>>>(packed, bucket_cnt, row_ptr, inv_deg, col, N, E);

    // --- fused casts / weight transposes ---
    prep_kernel<<<CAST_BLK + 320, 256, 0, stream>>>(x, xb, Ws0, Wn0, Ws1, Wn1, Ws2, Wn2,
                                                    BT0, BT1, BT2);

    int aggGrid = (int)(((long)N * 64 + 255) / 256);
    int gemmGrid = (N + 63) / 64;

    // --- layer 0: xb -> h1b ---
    agg_kernel<<<aggGrid, 256, 0, stream>>>(xb, row_ptr, col, inv_deg, aggb, N);
    mfma_gemm<128, true, true><<<gemmGrid, 256, 0, stream>>>(xb, aggb, BT0, b0, h1b, N);
    // --- layer 1: h1b -> xb (reuse) ---
    agg_kernel<<<aggGrid, 256, 0, stream>>>(h1b, row_ptr, col, inv_deg, aggb, N);
    mfma_gemm<128, true, true><<<gemmGrid, 256, 0, stream>>>(h1b, aggb, BT1, b1, xb, N);
    // --- layer 2: xb -> out (fp32) ---
    agg_kernel<<<aggGrid, 256, 0, stream>>>(xb, row_ptr, col, inv_deg, aggb, N);
    mfma_gemm<64, false, false><<<gemmGrid, 256, 0, stream>>>(xb, aggb, BT2, b2, out, N);
}